// Round 11
// baseline (107.811 us; speedup 1.0000x reference)
//
#include <hip/hip_runtime.h>
#include <hip/hip_bf16.h>

// Problem constants (B=1). All inputs/outputs are float32.
#define HH   96
#define WW   96
#define NPIX 9216          // 96*96
#define CH   128
#define NH   8
#define HD   16
#define KS   8

#define NPOS8   88         // 8 window rows x 11 window cols per 8-px segment
#define KVP     136        // kv LDS pitch in channels (272B/pos)
#define APITCH  132        // a-tile pitch in dwords (132 % 32 == 4 -> conflict-free)
#define PMPITCH 392        // conv LDS tile pitch in channels

__device__ __forceinline__ unsigned short f2bf(float f) {
    __hip_bfloat16 b = __float2bfloat16(f);
    union { __hip_bfloat16 b; unsigned short u; } cv; cv.b = b; return cv.u;
}
// unpack uint4 = 8 bf16 -> 8 fp32
__device__ __forceinline__ void u4_to_f8(uint4 u, float* f) {
    f[0] = __uint_as_float(u.x << 16); f[1] = __uint_as_float(u.x & 0xffff0000u);
    f[2] = __uint_as_float(u.y << 16); f[3] = __uint_as_float(u.y & 0xffff0000u);
    f[4] = __uint_as_float(u.z << 16); f[5] = __uint_as_float(u.z & 0xffff0000u);
    f[6] = __uint_as_float(u.w << 16); f[7] = __uint_as_float(u.w & 0xffff0000u);
}

// ---------------------------------------------------------------------------
// K1: fused depthwise 3x3 conv + transpose -> pixel-major [3][NPIX][CH] bf16.
// (R10 proven, unchanged) Quarter-row blocks: grid 384; block 256 thr.
// ---------------------------------------------------------------------------
__global__ __launch_bounds__(256) void conv_pm_kernel(
    const float* __restrict__ x,        // [128][96][96]
    const float* __restrict__ w,        // [384][1][3][3]
    const float* __restrict__ bias,     // [384]
    unsigned short* __restrict__ qkv_pm)// [3][NPIX][CH] bf16
{
    __shared__ unsigned short ldst[24 * PMPITCH];   // 18,816 B

    const int row = blockIdx.x >> 2;    // 0..95
    const int q   = blockIdx.x & 3;     // 0..3
    const int j0q = q * 24;
    const int tid = threadIdx.x;
    const int g   = tid >> 1;           // 0..127 input channel / group
    const int sh  = tid & 1;            // 0/1 -> 12 px each
    const int j0  = j0q + sh * 12;

    const float* xg = x + g * NPIX;

    float xr[3][14];
    #pragma unroll
    for (int dr = 0; dr < 3; ++dr) {
        const int r = row + dr - 1;
        if (r >= 0 && r < HH) {
            #pragma unroll
            for (int m = 0; m < 14; ++m) {
                const int j = j0 + m - 1;
                xr[dr][m] = (j >= 0 && j < WW) ? xg[r * WW + j] : 0.f;
            }
        } else {
            #pragma unroll
            for (int m = 0; m < 14; ++m) xr[dr][m] = 0.f;
        }
    }

    #pragma unroll
    for (int dt = 0; dt < 3; ++dt) {
        const int o = 3 * g + dt;       // conv out-channel (group g)
        float w9[9];
        #pragma unroll
        for (int k = 0; k < 9; ++k) w9[k] = w[o * 9 + k];
        const float b = bias[o];

        #pragma unroll
        for (int px = 0; px < 12; ++px) {
            float acc = b;
            #pragma unroll
            for (int kh = 0; kh < 3; ++kh)
                #pragma unroll
                for (int kw = 0; kw < 3; ++kw)
                    acc += xr[kh][px + kw] * w9[kh * 3 + kw];
            ldst[(sh * 12 + px) * PMPITCH + o] = f2bf(acc);
        }
    }

    __syncthreads();

    #pragma unroll
    for (int it = 0; it < 5; ++it) {
        const int idx = it * 256 + tid;
        if (idx < 1152) {
            const int px = idx / 48;
            const int c8 = idx - px * 48;
            const int o  = c8 * 8;
            const uint4 v = *(const uint4*)&ldst[px * PMPITCH + o];
            const int t = o >> 7, c = o & 127;
            *(uint4*)(qkv_pm + ((size_t)t * NPIX + row * WW + j0q + px) * CH + c) = v;
        }
    }
}

// ---------------------------------------------------------------------------
// K2: attention + block-local projection (no atomics).
// Block = 512 thr = 8 px x 8 heads x 8 window-row splits. wave = one head;
// lane = r*8 + px (butterfly masks 8/16/32 hit r bits). KV: full 128-ch
// union 88 pos, pitch 136 (r-lanes on distinct banks). After the merge the
// block owns a[8px][128ch] -> full projection locally: a-tile fp32 in LDS
// (aliases dead kv), pw read fp32 from L2 (broadcast in-wave), 2 outputs
// per thread, coalesced stores. Grid 1152.
// ---------------------------------------------------------------------------
__global__ __launch_bounds__(512) void attn_proj_kernel(
    const unsigned short* __restrict__ qkv_pm,  // [3][NPIX][CH] bf16
    const float* __restrict__ pw,               // [128][128] fp32 ([o][c])
    const float* __restrict__ pb,               // [128]
    float* __restrict__ out)                    // [128][NPIX] fp32
{
    __shared__ union SM {
        unsigned short kv[2][NPOS8 * KVP];      // 47,872 B
        float          al[8 * APITCH];          //  4,224 B (aliases kv)
    } sm;

    const int tid = threadIdx.x;
    const int seg = blockIdx.x;                 // 0..1151
    const int i   = seg / 12;                   // image row
    const int j0  = (seg - i * 12) * 8;
    const int rs     = 2 * min(max(i / 2 - 3, 0), 40);
    const int cs_min = 2 * min(max(j0 / 2 - 3, 0), 40);

    // ---- stage K,V: 2 kv x 88 pos x 16 uint4 = 2816 tasks ----
    #pragma unroll
    for (int it = 0; it < 6; ++it) {
        const int idx = it * 512 + tid;
        if (idx < 2816) {
            const int kvsel = idx / 1408;       // wave-uniform (1408 = 22 waves)
            const int rem   = idx - kvsel * 1408;
            const int pos   = rem >> 4;         // 0..87
            const int sub   = rem & 15;
            const int p     = pos / 11;
            const int cc    = pos - p * 11;
            const int pixg  = (rs + 2 * p) * WW + cs_min + 2 * cc;  // <= 9124 < NPIX
            *(uint4*)&sm.kv[kvsel][pos * KVP + sub * 8] =
                *(const uint4*)(qkv_pm + ((size_t)(1 + kvsel) * NPIX + pixg) * CH + sub * 8);
        }
    }

    // ---- per-thread coordinates: wave = head, lane = r*8 + px ----
    const int lane = tid & 63;
    const int h    = tid >> 6;                  // 0..7
    const int px   = lane & 7;
    const int r    = lane >> 3;                 // window-row split
    const int pix  = seg * 8 + px;
    const int j    = j0 + px;
    const int ci0  = (2 * min(max(j / 2 - 3, 0), 40) - cs_min) >> 1;  // 0..3

    float qr[HD];
    {
        const unsigned short* qp = qkv_pm + (size_t)pix * CH + h * HD;
        u4_to_f8(*(const uint4*)qp, qr);
        u4_to_f8(*(const uint4*)(qp + 8), qr + 8);
        #pragma unroll
        for (int d = 0; d < HD; ++d) qr[d] *= 0.25f;   // HD^-0.5
    }

    __syncthreads();

    // ---- QK^T for this thread's window row ----
    const int posr = r * 11 + ci0;
    float lg[KS];
    float m = -1e30f;
    #pragma unroll
    for (int q = 0; q < KS; ++q) {
        const unsigned short* kp = &sm.kv[0][(posr + q) * KVP + h * HD];
        float kf[HD];
        u4_to_f8(*(const uint4*)kp, kf);
        u4_to_f8(*(const uint4*)(kp + 8), kf + 8);
        float acc = 0.f;
        #pragma unroll
        for (int d = 0; d < HD; ++d) acc += qr[d] * kf[d];
        lg[q] = acc;
        m = fmaxf(m, acc);
    }

    float s = 0.f;
    #pragma unroll
    for (int q = 0; q < KS; ++q) { lg[q] = __expf(lg[q] - m); s += lg[q]; }

    // ---- partial PV ----
    float o[HD];
    #pragma unroll
    for (int d = 0; d < HD; ++d) o[d] = 0.f;
    #pragma unroll
    for (int q = 0; q < KS; ++q) {
        const unsigned short* vp = &sm.kv[1][(posr + q) * KVP + h * HD];
        float vf[HD];
        u4_to_f8(*(const uint4*)vp, vf);
        u4_to_f8(*(const uint4*)(vp + 8), vf + 8);
        const float wgt = lg[q];
        #pragma unroll
        for (int d = 0; d < HD; ++d) o[d] += wgt * vf[d];
    }

    // ---- online-softmax butterfly merge across r (lane bits 3..5) ----
    #pragma unroll
    for (int mask = 8; mask <= 32; mask <<= 1) {
        const float m2 = __shfl_xor(m, mask);
        const float s2 = __shfl_xor(s, mask);
        const float mn = fmaxf(m, m2);
        const float ea = __expf(m - mn);
        const float eb = __expf(m2 - mn);
        s = s * ea + s2 * eb;
        #pragma unroll
        for (int d = 0; d < HD; ++d) {
            const float o2 = __shfl_xor(o[d], mask);
            o[d] = o[d] * ea + o2 * eb;
        }
        m = mn;
    }
    const float inv = 1.f / s;

    // ---- a-tile to LDS (kv dead after this barrier) ----
    __syncthreads();
    sm.al[px * APITCH + h * HD + 2 * r]     = o[2 * r]     * inv;
    sm.al[px * APITCH + h * HD + 2 * r + 1] = o[2 * r + 1] * inv;
    __syncthreads();

    // ---- block-local projection: thread = (o-pair = tid>>3, px2 = tid&7) ----
    const int px2 = tid & 7;
    const int o0  = (tid >> 3) * 2;             // 0,2,...,126

    float a0 = pb[o0], a1 = pb[o0 + 1];
    #pragma unroll
    for (int c0 = 0; c0 < CH; c0 += 4) {
        const float4 av = *(const float4*)&sm.al[px2 * APITCH + c0];
        const float4 w0 = *(const float4*)(pw + (size_t)(o0)     * CH + c0);
        const float4 w1 = *(const float4*)(pw + (size_t)(o0 + 1) * CH + c0);
        a0 += av.x * w0.x + av.y * w0.y + av.z * w0.z + av.w * w0.w;
        a1 += av.x * w1.x + av.y * w1.y + av.z * w1.z + av.w * w1.w;
    }

    out[(size_t)(o0)     * NPIX + seg * 8 + px2] = a0;
    out[(size_t)(o0 + 1) * NPIX + seg * 8 + px2] = a1;
}

// ---------------------------------------------------------------------------
extern "C" void kernel_launch(void* const* d_in, const int* in_sizes, int n_in,
                              void* d_out, int out_size, void* d_ws, size_t ws_size,
                              hipStream_t stream)
{
    const float* x      = (const float*)d_in[0];
    const float* qkv_w  = (const float*)d_in[1];
    const float* qkv_b  = (const float*)d_in[2];
    const float* proj_w = (const float*)d_in[3];
    const float* proj_b = (const float*)d_in[4];
    float* out = (float*)d_out;

    unsigned short* qkv_pm = (unsigned short*)d_ws;   // [3][NPIX][CH] bf16 (7.08 MB)

    conv_pm_kernel  <<<384, 256, 0, stream>>>(x, qkv_w, qkv_b, qkv_pm);
    attn_proj_kernel<<<1152, 512, 0, stream>>>(qkv_pm, proj_w, proj_b, out);
}

// Round 12
// 105.595 us; speedup vs baseline: 1.0210x; 1.0210x over previous
//
#include <hip/hip_runtime.h>
#include <hip/hip_bf16.h>

// Problem constants (B=1). All inputs/outputs are float32.
#define HH   96
#define WW   96
#define NPIX 9216          // 96*96
#define CH   128
#define NH   8
#define HD   16
#define KS   8

#define NPOS    120        // 8 window rows x 15 window cols per 16-px segment
#define KVPITCH 40         // attn LDS pitch in channels (80B/pos)
#define PMPITCH 392        // conv LDS tile pitch in channels

__device__ __forceinline__ unsigned short f2bf(float f) {
    __hip_bfloat16 b = __float2bfloat16(f);
    union { __hip_bfloat16 b; unsigned short u; } cv; cv.b = b; return cv.u;
}
// unpack uint4 = 8 bf16 -> 8 fp32
__device__ __forceinline__ void u4_to_f8(uint4 u, float* f) {
    f[0] = __uint_as_float(u.x << 16); f[1] = __uint_as_float(u.x & 0xffff0000u);
    f[2] = __uint_as_float(u.y << 16); f[3] = __uint_as_float(u.y & 0xffff0000u);
    f[4] = __uint_as_float(u.z << 16); f[5] = __uint_as_float(u.z & 0xffff0000u);
    f[6] = __uint_as_float(u.w << 16); f[7] = __uint_as_float(u.w & 0xffff0000u);
}

// ---------------------------------------------------------------------------
// K1: fused depthwise 3x3 conv + transpose -> pixel-major [3][NPIX][CH] bf16.
// (R10/R11 proven) Quarter-row blocks: grid 384; block 256 thr.
// ---------------------------------------------------------------------------
__global__ __launch_bounds__(256) void conv_pm_kernel(
    const float* __restrict__ x,        // [128][96][96]
    const float* __restrict__ w,        // [384][1][3][3]
    const float* __restrict__ bias,     // [384]
    unsigned short* __restrict__ qkv_pm)// [3][NPIX][CH] bf16
{
    __shared__ unsigned short ldst[24 * PMPITCH];   // 18,816 B

    const int row = blockIdx.x >> 2;    // 0..95
    const int q   = blockIdx.x & 3;     // 0..3
    const int j0q = q * 24;
    const int tid = threadIdx.x;
    const int g   = tid >> 1;           // 0..127 input channel / group
    const int sh  = tid & 1;            // 0/1 -> 12 px each
    const int j0  = j0q + sh * 12;

    const float* xg = x + g * NPIX;

    float xr[3][14];
    #pragma unroll
    for (int dr = 0; dr < 3; ++dr) {
        const int r = row + dr - 1;
        if (r >= 0 && r < HH) {
            #pragma unroll
            for (int m = 0; m < 14; ++m) {
                const int j = j0 + m - 1;
                xr[dr][m] = (j >= 0 && j < WW) ? xg[r * WW + j] : 0.f;
            }
        } else {
            #pragma unroll
            for (int m = 0; m < 14; ++m) xr[dr][m] = 0.f;
        }
    }

    #pragma unroll
    for (int dt = 0; dt < 3; ++dt) {
        const int o = 3 * g + dt;       // conv out-channel (group g)
        float w9[9];
        #pragma unroll
        for (int k = 0; k < 9; ++k) w9[k] = w[o * 9 + k];
        const float b = bias[o];

        #pragma unroll
        for (int px = 0; px < 12; ++px) {
            float acc = b;
            #pragma unroll
            for (int kh = 0; kh < 3; ++kh)
                #pragma unroll
                for (int kw = 0; kw < 3; ++kw)
                    acc += xr[kh][px + kw] * w9[kh * 3 + kw];
            ldst[(sh * 12 + px) * PMPITCH + o] = f2bf(acc);
        }
    }

    __syncthreads();

    #pragma unroll
    for (int it = 0; it < 5; ++it) {
        const int idx = it * 256 + tid;
        if (idx < 1152) {
            const int px = idx / 48;
            const int c8 = idx - px * 48;
            const int o  = c8 * 8;
            const uint4 v = *(const uint4*)&ldst[px * PMPITCH + o];
            const int t = o >> 7, c = o & 127;
            *(uint4*)(qkv_pm + ((size_t)t * NPIX + row * WW + j0q + px) * CH + c) = v;
        }
    }
}

// ---------------------------------------------------------------------------
// K2: neighborhood attention, head-pair blocks. (R8 proven, byte-identical)
// Grid (576 segs, 4 head-pairs); block = 256 thr = 16 px x 2 heads x 8 r.
// LDS 19.2 KB -> 8 blocks/CU = 32 waves/CU. Merge across r via __shfl_xor.
// ---------------------------------------------------------------------------
__global__ __launch_bounds__(256) void attn_kernel(
    const unsigned short* __restrict__ qkv_pm,  // [3][NPIX][CH] bf16
    float* __restrict__ a_t)                    // [CH][NPIX] fp32
{
    __shared__ unsigned short kv[2][NPOS * KVPITCH];   // 19,200 B

    const int tid = threadIdx.x;
    const int seg = blockIdx.x;                 // 0..575
    const int hp  = blockIdx.y;                 // head pair 0..3
    const int i   = seg / 6;                    // image row
    const int j0  = (seg - i * 6) * 16;
    const int rs     = 2 * min(max(i / 2 - 3, 0), 40);
    const int cs_min = 2 * min(max(j0 / 2 - 3, 0), 40);

    // ---- stage K,V head-pair slice: 960 uint4 tasks ----
    #pragma unroll
    for (int it = 0; it < 4; ++it) {
        const int idx = it * 256 + tid;
        if (idx < 960) {
            const int kvsel = idx / 480;
            const int rem   = idx - kvsel * 480;
            const int pos   = rem >> 2;
            const int sub   = rem & 3;
            const int p     = pos / 15;
            const int cc    = pos - p * 15;
            const int pixg  = (rs + 2 * p) * WW + cs_min + 2 * cc;  // < NPIX
            *(uint4*)&kv[kvsel][pos * KVPITCH + sub * 8] =
                *(const uint4*)(qkv_pm + ((size_t)(1 + kvsel) * NPIX + pixg) * CH
                                + hp * 32 + sub * 8);
        }
    }

    // ---- per-thread coordinates: lane = r*8 + hh*4 + px_lo ----
    const int lane  = tid & 63;
    const int wave  = tid >> 6;                 // 0..3
    const int r     = lane >> 3;                // window-row split
    const int hh    = (lane >> 2) & 1;          // head within pair
    const int px    = wave * 4 + (lane & 3);    // 0..15
    const int h     = hp * 2 + hh;
    const int pix   = seg * 16 + px;
    const int j     = j0 + px;
    const int ci0   = (2 * min(max(j / 2 - 3, 0), 40) - cs_min) >> 1;  // 0..7

    float qr[HD];
    {
        const unsigned short* qp = qkv_pm + (size_t)pix * CH + h * HD;
        u4_to_f8(*(const uint4*)qp, qr);
        u4_to_f8(*(const uint4*)(qp + 8), qr + 8);
        #pragma unroll
        for (int d = 0; d < HD; ++d) qr[d] *= 0.25f;   // HD^-0.5
    }

    __syncthreads();

    const int posr = r * 15 + ci0;
    float lg[KS];
    float m = -1e30f;
    #pragma unroll
    for (int q = 0; q < KS; ++q) {
        const unsigned short* kp = &kv[0][(posr + q) * KVPITCH + hh * HD];
        float kf[HD];
        u4_to_f8(*(const uint4*)kp, kf);
        u4_to_f8(*(const uint4*)(kp + 8), kf + 8);
        float acc = 0.f;
        #pragma unroll
        for (int d = 0; d < HD; ++d) acc += qr[d] * kf[d];
        lg[q] = acc;
        m = fmaxf(m, acc);
    }

    float s = 0.f;
    #pragma unroll
    for (int q = 0; q < KS; ++q) { lg[q] = __expf(lg[q] - m); s += lg[q]; }

    float o[HD];
    #pragma unroll
    for (int d = 0; d < HD; ++d) o[d] = 0.f;
    #pragma unroll
    for (int q = 0; q < KS; ++q) {
        const unsigned short* vp = &kv[1][(posr + q) * KVPITCH + hh * HD];
        float vf[HD];
        u4_to_f8(*(const uint4*)vp, vf);
        u4_to_f8(*(const uint4*)(vp + 8), vf + 8);
        const float wgt = lg[q];
        #pragma unroll
        for (int d = 0; d < HD; ++d) o[d] += wgt * vf[d];
    }

    #pragma unroll
    for (int mask = 8; mask <= 32; mask <<= 1) {
        const float m2 = __shfl_xor(m, mask);
        const float s2 = __shfl_xor(s, mask);
        const float mn = fmaxf(m, m2);
        const float ea = __expf(m - mn);
        const float eb = __expf(m2 - mn);
        s = s * ea + s2 * eb;
        #pragma unroll
        for (int d = 0; d < HD; ++d) {
            const float o2 = __shfl_xor(o[d], mask);
            o[d] = o[d] * ea + o2 * eb;
        }
        m = mn;
    }
    const float inv = 1.f / s;

    a_t[(size_t)(h * HD + 2 * r)     * NPIX + pix] = o[2 * r]     * inv;
    a_t[(size_t)(h * HD + 2 * r + 1) * NPIX + pix] = o[2 * r + 1] * inv;
}

// ---------------------------------------------------------------------------
// K3: 1x1 projection, ILP layout (R9 proven): thread = (o-pair wave-uniform
// -> scalar pw loads, 4 px float4). Grid 576 x 256.
// ---------------------------------------------------------------------------
__global__ __launch_bounds__(256) void proj_kernel(
    const float* __restrict__ a_t,      // [CH][NPIX]
    const float* __restrict__ pw,       // [128][128] ([o][c])
    const float* __restrict__ pb,       // [128]
    float* __restrict__ out)            // [128][NPIX]
{
    const int idx = blockIdx.x * 256 + threadIdx.x;
    const int op  = __builtin_amdgcn_readfirstlane(idx / 2304);  // 0..63
    const int pq  = idx - op * 2304;
    const int px0 = pq * 4;
    const int o0  = op * 2;

    float acc0[4], acc1[4];
    #pragma unroll
    for (int e = 0; e < 4; ++e) { acc0[e] = pb[o0]; acc1[e] = pb[o0 + 1]; }

    for (int c = 0; c < CH; ++c) {
        const float4 a  = *(const float4*)(a_t + (size_t)c * NPIX + px0);
        const float  w0 = pw[(o0)     * CH + c];
        const float  w1 = pw[(o0 + 1) * CH + c];
        acc0[0] += a.x * w0; acc0[1] += a.y * w0; acc0[2] += a.z * w0; acc0[3] += a.w * w0;
        acc1[0] += a.x * w1; acc1[1] += a.y * w1; acc1[2] += a.z * w1; acc1[3] += a.w * w1;
    }

    *(float4*)(out + (size_t)(o0)     * NPIX + px0) = make_float4(acc0[0], acc0[1], acc0[2], acc0[3]);
    *(float4*)(out + (size_t)(o0 + 1) * NPIX + px0) = make_float4(acc1[0], acc1[1], acc1[2], acc1[3]);
}

// ---------------------------------------------------------------------------
extern "C" void kernel_launch(void* const* d_in, const int* in_sizes, int n_in,
                              void* d_out, int out_size, void* d_ws, size_t ws_size,
                              hipStream_t stream)
{
    const float* x      = (const float*)d_in[0];
    const float* qkv_w  = (const float*)d_in[1];
    const float* qkv_b  = (const float*)d_in[2];
    const float* proj_w = (const float*)d_in[3];
    const float* proj_b = (const float*)d_in[4];
    float* out = (float*)d_out;

    unsigned short* qkv_pm = (unsigned short*)d_ws;            // [3][NPIX][CH] bf16 (7.08 MB)
    float*          a_t    = (float*)(qkv_pm + 3 * NPIX * CH); // [CH][NPIX] fp32 (4.72 MB)

    conv_pm_kernel<<<384, 256, 0, stream>>>(x, qkv_w, qkv_b, qkv_pm);
    attn_kernel   <<<dim3(576, 4), 256, 0, stream>>>(qkv_pm, a_t);
    proj_kernel   <<<576, 256, 0, stream>>>(a_t, proj_w, proj_b, out);
}